// Round 4
// baseline (149.714 us; speedup 1.0000x reference)
//
#include <hip/hip_runtime.h>
#include <hip/hip_bf16.h>
#include <cstdint>
#include <cstddef>

#define BN_EPS 1e-5f

typedef float f32x4_t __attribute__((ext_vector_type(4)));
typedef __bf16 bf16x8_t __attribute__((ext_vector_type(8)));

__device__ __forceinline__ unsigned short f2bf(float f) {
    __hip_bfloat16 h = __float2bfloat16(f);
    return __builtin_bit_cast(unsigned short, h);
}

// async global->LDS, 16B/lane; LDS dest is wave-uniform base + lane*16.
__device__ __forceinline__ void gld_lds16(void* lds, const void* gp) {
#if __has_builtin(__builtin_amdgcn_global_load_lds)
    __builtin_amdgcn_global_load_lds(
        (const __attribute__((address_space(1))) unsigned int*)gp,
        (__attribute__((address_space(3))) unsigned int*)lds, 16, 0, 0);
#else
    *(uint4*)lds = *(const uint4*)gp;
#endif
}

// ---------------- ws layout ----------------
// kp     : float [T][CI][CO]              32768 f
// escale : float [B][T][N]                65536 f
// bns    : float sum[64]+sumsq[64]        128 f
// He2    : float [2 part][B*N][64]        1048576 f  (4 MB)
// G      : bf16  [B][N][N]                8388608 us (16 MB)
// bmatT  : bf16  [B][512 col][N(m)]       4194304 us (8 MB)
// total ~28.6 MB

// K0: repack k_tensor (CO,CI,T) -> kp[t][c][o]; also zero bns (replaces memset)
__global__ __launch_bounds__(256) void k_pack(const float* __restrict__ k,
                                              float* __restrict__ kp,
                                              float* __restrict__ bns) {
    int i = blockIdx.x * 256 + threadIdx.x;   // 32768 total
    int o = i & 63;
    int c = (i >> 6) & 63;
    int t = i >> 12;
    kp[i] = k[(o * 64 + c) * 8 + t];
    if (blockIdx.x == 0 && threadIdx.x < 128) bns[threadIdx.x] = 0.f;
}

// K1 (fused k_g + k_prep): per (b, 32-row chunk):
//   G rows (bf16, each exp once) + rowsum -> w -> sfac*(w@k_t^T) -> bmatT; escale
__global__ __launch_bounds__(256) void k_gp(const float* __restrict__ points,
                                            const float* __restrict__ trans,
                                            const float* __restrict__ funcs,
                                            const float* __restrict__ kp,
                                            unsigned short* __restrict__ G,
                                            unsigned short* __restrict__ bmatT,
                                            float* __restrict__ escale) {
    __shared__ union {
        float praw[3072];
        unsigned short tile[16384];   // [col(512)][m(32)] bf16
    } u;
    __shared__ float px[1024], py[1024], pz[1024], hq[1024];
    __shared__ float rs[32];
    __shared__ float ktl[4096];
    __shared__ float wl[2048];        // [m(32)][c(64)]
    __shared__ float sfac[256];       // [t(8)][m(32)]
    __shared__ float trl[24];
    __shared__ float tsql[8];

    const int b  = blockIdx.x & 7;               // XCD swizzle
    const int m0 = (blockIdx.x >> 3) * 32;
    const int tid = threadIdx.x;

    for (int i = tid; i < 3072; i += 256) u.praw[i] = points[b * 3072 + i];
    if (tid < 24) trl[tid] = trans[b * 24 + tid];
    if (tid < 32) rs[tid] = 0.f;
    __syncthreads();
    for (int n = tid; n < 1024; n += 256) {
        float x = u.praw[n * 3], y = u.praw[n * 3 + 1], z = u.praw[n * 3 + 2];
        px[n] = x; py[n] = y; pz[n] = z;
        hq[n] = -0.5f * (x * x + y * y + z * z);
    }
    if (tid < 8) {
        float x = trl[tid * 3], y = trl[tid * 3 + 1], z = trl[tid * 3 + 2];
        tsql[tid] = x * x + y * y + z * z;
    }
    __syncthreads();                  // px/hq ready; praw region now free

    // ---- G rows + rowsum ----
    {
        const int rhalf = tid >> 7;
        const int c0 = (tid & 127) * 8;
        unsigned short* gb = G + ((size_t)b << 20);
        for (int uu = 0; uu < 16; ++uu) {
            const int rl = uu * 2 + rhalf;
            const int row = m0 + rl;
            const float rx = px[row], ry = py[row], rz = pz[row], hr = hq[row];
            float vx[8], vy[8], vz[8], vh[8];
            *(float4*)&vx[0] = *(const float4*)&px[c0];
            *(float4*)&vx[4] = *(const float4*)&px[c0 + 4];
            *(float4*)&vy[0] = *(const float4*)&py[c0];
            *(float4*)&vy[4] = *(const float4*)&py[c0 + 4];
            *(float4*)&vz[0] = *(const float4*)&pz[c0];
            *(float4*)&vz[4] = *(const float4*)&pz[c0 + 4];
            *(float4*)&vh[0] = *(const float4*)&hq[c0];
            *(float4*)&vh[4] = *(const float4*)&hq[c0 + 4];
            unsigned short us[8];
            float ssum = 0.f;
            #pragma unroll
            for (int j = 0; j < 8; ++j) {
                float e = __expf(hr + vh[j] + rx * vx[j] + ry * vy[j] + rz * vz[j]);
                ssum += e;
                us[j] = f2bf(e);
            }
            uint4 pk;
            pk.x = us[0] | ((unsigned int)us[1] << 16);
            pk.y = us[2] | ((unsigned int)us[3] << 16);
            pk.z = us[4] | ((unsigned int)us[5] << 16);
            pk.w = us[6] | ((unsigned int)us[7] << 16);
            *(uint4*)(gb + (size_t)row * 1024 + c0) = pk;
            #pragma unroll
            for (int m = 32; m; m >>= 1) ssum += __shfl_xor(ssum, m, 64);
            if ((tid & 63) == 0) atomicAdd(&rs[rl], ssum);
        }
    }
    __syncthreads();                  // rowsum final

    // ---- w = funcs / rowsum ----
    #pragma unroll
    for (int half = 0; half < 2; ++half) {
        const int m = half * 16 + (tid >> 4), c4 = (tid & 15) * 4;
        const float4 f = *(const float4*)&funcs[((size_t)(b * 1024) + m0 + m) * 64 + c4];
        const float inv = 1.f / rs[m];
        *(float4*)&wl[m * 64 + c4] = make_float4(f.x * inv, f.y * inv, f.z * inv, f.w * inv);
    }
    // ---- sfac / escale ----
    {
        const int t = tid >> 5, m = tid & 31;
        const int n = m0 + m;
        const float ptd = px[n] * trl[t * 3] + py[n] * trl[t * 3 + 1] + pz[n] * trl[t * 3 + 2];
        sfac[t * 32 + m] = __expf(-ptd - 0.5f * tsql[t]);
        escale[(size_t)(b * 8 + t) * 1024 + n] = __expf(ptd);
    }

    // ---- C_t GEMM into tile ----
    for (int t = 0; t < 8; ++t) {
        __syncthreads();              // wl/sfac visible (t=0); ktl free (t>0)
        for (int i = tid; i < 4096; i += 256) ktl[i] = kp[t * 4096 + i];
        __syncthreads();
        #pragma unroll
        for (int half = 0; half < 2; ++half) {
            const int m = half * 16 + (tid >> 4), o4 = (tid & 15) * 4;
            float4 acc = make_float4(0.f, 0.f, 0.f, 0.f);
            const float* wrow = &wl[m * 64];
            #pragma unroll 8
            for (int c = 0; c < 64; ++c) {
                float wv = wrow[c];
                float4 k4 = *(const float4*)&ktl[c * 64 + o4];
                acc.x += wv * k4.x; acc.y += wv * k4.y;
                acc.z += wv * k4.z; acc.w += wv * k4.w;
            }
            const float sf = sfac[t * 32 + m];
            u.tile[(t * 64 + o4 + 0) * 32 + m] = f2bf(acc.x * sf);
            u.tile[(t * 64 + o4 + 1) * 32 + m] = f2bf(acc.y * sf);
            u.tile[(t * 64 + o4 + 2) * 32 + m] = f2bf(acc.z * sf);
            u.tile[(t * 64 + o4 + 3) * 32 + m] = f2bf(acc.w * sf);
        }
    }
    __syncthreads();
    // ---- store bmatT[b][col][m0..m0+31] ----
    #pragma unroll
    for (int it = 0; it < 8; ++it) {
        const int L = it * 256 + tid;
        const int col = L >> 2, q = L & 3;
        uint4 v = *(const uint4*)((const char*)u.tile + col * 64 + q * 16);
        *(uint4*)(bmatT + (size_t)(b * 512 + col) * 1024 + m0 + q * 8) = v;
    }
}

// K2: bf16 GEMM with global_load_lds staging + XOR-4 k-group swizzle.
// grid 512 = b(8) x rt(8) x [og(4) x kh(2)]; 256 thr = 4 waves; 128x128 tile, BK=32.
// Block's 128 B-cols = all 8 t x 16 channels (og) -> full t-reduction in-block.
// Epilogue: *escale, sum over t, cross-wave reduce, write fp32 partial He2[kh].
__global__ __launch_bounds__(256) void k_gemm(const unsigned short* __restrict__ G,
                                              const unsigned short* __restrict__ bmatT,
                                              const float* __restrict__ escale,
                                              float* __restrict__ He2) {
    __shared__ unsigned short As[4096];   // [row(128)][k(32)] bf16, k-swizzled
    __shared__ unsigned short Bs[4096];   // [c'(128)=t*16+oo][k(32)] bf16, k-swizzled
    __shared__ float escT[1024];          // [t(8)][row(128)]
    __shared__ float red[128 * 20];       // padded reduce tile [row][16ch]

    const int b  = blockIdx.x & 7;        // XCD swizzle
    const int rt = (blockIdx.x >> 3) & 7;
    const int z  = blockIdx.x >> 6;       // 0..7
    const int og = z & 3;                 // channel group (16 ch)
    const int kh = z >> 2;                // K half
    const int n0 = rt * 128;
    const int kb = kh * 512;

    const int tid  = threadIdx.x;
    const int wave = tid >> 6, lane = tid & 63;
    const int wr = wave >> 1, wc = wave & 1;

    {   // stage escale [8t][128 rows]
        const int t = tid >> 5, r4 = (tid & 31) * 4;
        *(float4*)&escT[t * 128 + r4] =
            *(const float4*)&escale[(size_t)(b * 8 + t) * 1024 + n0 + r4];
    }

    const unsigned short* gA = G + ((size_t)b << 20) + (size_t)n0 * 1024 + kb;
    const unsigned short* gB = bmatT + (size_t)(b * 512 + og * 16) * 1024 + kb;

    const int r16 = lane >> 2;            // row within 16-seg
    const int kq  = lane & 3;             // dest 16B k-group
    const int gsw = kq ^ (r16 & 3);       // swizzled source k-group
    const size_t gAoff = (size_t)r16 * 1024 + gsw * 8;

    f32x4_t acc[4][4];
    #pragma unroll
    for (int i = 0; i < 4; ++i)
        #pragma unroll
        for (int j = 0; j < 4; ++j) acc[i][j] = f32x4_t{0.f, 0.f, 0.f, 0.f};

    const int fr = lane & 15;             // fragment row/col part
    const int swoff = ((lane >> 4) ^ (fr & 3)) << 4;   // swizzled frag byte offset

    for (int kk = 0; kk < 16; ++kk) {
        const int k0 = kk * 32;
        __syncthreads();                  // all waves done with prev As/Bs
        #pragma unroll
        for (int i = 0; i < 2; ++i) {
            const int seg = wave * 2 + i;   // 16 rows (A) / one t: 16 cols (B)
            gld_lds16((char*)As + seg * 1024 + lane * 16,
                      gA + (size_t)(seg * 16) * 1024 + k0 + gAoff);
            gld_lds16((char*)Bs + seg * 1024 + lane * 16,
                      gB + (size_t)(seg * 64) * 1024 + (size_t)r16 * 1024 + k0 + gsw * 8);
        }
        __syncthreads();                  // DMA drained -> tiles visible
        uint4 afr[4], bfr[4];
        #pragma unroll
        for (int i = 0; i < 4; ++i)
            afr[i] = *(const uint4*)((const char*)As + (wr * 64 + i * 16 + fr) * 64 + swoff);
        #pragma unroll
        for (int j = 0; j < 4; ++j)
            bfr[j] = *(const uint4*)((const char*)Bs + (wc * 64 + j * 16 + fr) * 64 + swoff);
        #pragma unroll
        for (int i = 0; i < 4; ++i)
            #pragma unroll
            for (int j = 0; j < 4; ++j)
                acc[i][j] = __builtin_amdgcn_mfma_f32_16x16x32_bf16(
                    __builtin_bit_cast(bf16x8_t, afr[i]),
                    __builtin_bit_cast(bf16x8_t, bfr[j]),
                    acc[i][j], 0, 0, 0);
    }

    // epilogue: res[row][oo] = sum_j escale[wc*4+j][row] * acc[.][j][.]
    const int quad = lane >> 4, oo = lane & 15;
    float res[4][4];
    #pragma unroll
    for (int i = 0; i < 4; ++i)
        #pragma unroll
        for (int r = 0; r < 4; ++r) {
            const int lr = wr * 64 + i * 16 + quad * 4 + r;
            float s = 0.f;
            #pragma unroll
            for (int j = 0; j < 4; ++j)
                s += escT[(wc * 4 + j) * 128 + lr] * acc[i][j][r];
            res[i][r] = s;
        }
    if (wc == 0) {
        #pragma unroll
        for (int i = 0; i < 4; ++i)
            #pragma unroll
            for (int r = 0; r < 4; ++r) {
                const int lr = wr * 64 + i * 16 + quad * 4 + r;
                red[lr * 20 + oo] = res[i][r];
            }
    }
    __syncthreads();
    if (wc == 1) {
        #pragma unroll
        for (int i = 0; i < 4; ++i)
            #pragma unroll
            for (int r = 0; r < 4; ++r) {
                const int lr = wr * 64 + i * 16 + quad * 4 + r;
                red[lr * 20 + oo] += res[i][r];
            }
    }
    __syncthreads();
    float* dst = He2 + (size_t)kh * 524288 + (size_t)(b * 1024 + n0) * 64 + og * 16;
    #pragma unroll
    for (int it = 0; it < 2; ++it) {
        const int L = it * 256 + tid;
        const int row = L >> 2, c4 = (L & 3) * 4;
        *(float4*)(dst + (size_t)row * 64 + c4) = *(const float4*)&red[row * 20 + c4];
    }
}

// K3: out = He2[0] + He2[1]; fused BN sum/sumsq
__global__ __launch_bounds__(256) void k_fin(const float* __restrict__ He2,
                                             float* __restrict__ out,
                                             float* __restrict__ bns) {
    __shared__ float s1[16][64], s2[16][64];
    const int tid = threadIdx.x;
    const float4* H4 = (const float4*)He2;
    float a0 = 0.f, a1 = 0.f, a2 = 0.f, a3 = 0.f;
    float q0 = 0.f, q1 = 0.f, q2 = 0.f, q3 = 0.f;
    #pragma unroll
    for (int it = 0; it < 2; ++it) {
        const size_t idx = (size_t)blockIdx.x * 512 + it * 256 + tid;
        float4 p0 = H4[idx];
        float4 p1 = H4[131072 + idx];
        float4 s = make_float4(p0.x + p1.x, p0.y + p1.y, p0.z + p1.z, p0.w + p1.w);
        ((float4*)out)[idx] = s;
        a0 += s.x; a1 += s.y; a2 += s.z; a3 += s.w;
        q0 += s.x * s.x; q1 += s.y * s.y; q2 += s.z * s.z; q3 += s.w * s.w;
    }
    const int g = tid >> 4, o4 = (tid & 15) * 4;
    *(float4*)&s1[g][o4] = make_float4(a0, a1, a2, a3);
    *(float4*)&s2[g][o4] = make_float4(q0, q1, q2, q3);
    __syncthreads();
    if (tid < 64) {
        float sa = 0.f, sb = 0.f;
        #pragma unroll
        for (int r = 0; r < 16; ++r) { sa += s1[r][tid]; sb += s2[r][tid]; }
        atomicAdd(&bns[tid], sa);
        atomicAdd(&bns[64 + tid], sb);
    }
}

// K4: in-place BN (training stats) + ReLU
__global__ __launch_bounds__(256) void k_bn(float* __restrict__ out,
                                            const float* __restrict__ bns,
                                            const float* __restrict__ gamma,
                                            const float* __restrict__ beta) {
    const int i = blockIdx.x * 256 + threadIdx.x;
    const int o4 = (i & 15) * 4;
    float4 x = ((float4*)out)[i];
    const float4 s  = *(const float4*)&bns[o4];
    const float4 s2 = *(const float4*)&bns[64 + o4];
    const float4 gm = *(const float4*)&gamma[o4];
    const float4 bt = *(const float4*)&beta[o4];
    const float invn = 1.f / 8192.f;
    float m, v, w;
    m = s.x * invn; v = s2.x * invn - m * m; w = __frsqrt_rn(v + BN_EPS) * gm.x;
    x.x = fmaxf((x.x - m) * w + bt.x, 0.f);
    m = s.y * invn; v = s2.y * invn - m * m; w = __frsqrt_rn(v + BN_EPS) * gm.y;
    x.y = fmaxf((x.y - m) * w + bt.y, 0.f);
    m = s.z * invn; v = s2.z * invn - m * m; w = __frsqrt_rn(v + BN_EPS) * gm.z;
    x.z = fmaxf((x.z - m) * w + bt.z, 0.f);
    m = s.w * invn; v = s2.w * invn - m * m; w = __frsqrt_rn(v + BN_EPS) * gm.w;
    x.w = fmaxf((x.w - m) * w + bt.w, 0.f);
    ((float4*)out)[i] = x;
}

extern "C" void kernel_launch(void* const* d_in, const int* in_sizes, int n_in,
                              void* d_out, int out_size, void* d_ws, size_t ws_size,
                              hipStream_t stream) {
    const float* points = (const float*)d_in[0];
    const float* trans  = (const float*)d_in[1];
    const float* funcs  = (const float*)d_in[2];
    const float* ktens  = (const float*)d_in[3];
    const float* gamma  = (const float*)d_in[4];
    const float* beta   = (const float*)d_in[5];
    float* out = (float*)d_out;

    float* ws      = (float*)d_ws;
    float* kp      = ws;                    // 32768 f
    float* escale  = kp + 32768;            // 65536 f
    float* bns     = escale + 65536;        // 128 f
    float* He2     = bns + 128;             // 1048576 f
    unsigned short* G     = (unsigned short*)(He2 + 1048576);   // 8388608 us
    unsigned short* bmatT = G + 8388608;                        // 4194304 us

    k_pack<<<128, 256, 0, stream>>>(ktens, kp, bns);
    k_gp<<<256, 256, 0, stream>>>(points, trans, funcs, kp, G, bmatT, escale);
    k_gemm<<<512, 256, 0, stream>>>(G, bmatT, escale, He2);
    k_fin<<<256, 256, 0, stream>>>(He2, out, bns);
    k_bn<<<512, 256, 0, stream>>>(out, bns, gamma, beta);
}

// Round 5
// 143.337 us; speedup vs baseline: 1.0445x; 1.0445x over previous
//
#include <hip/hip_runtime.h>
#include <hip/hip_bf16.h>
#include <cstdint>
#include <cstddef>

#define BN_EPS 1e-5f

typedef float f32x4_t __attribute__((ext_vector_type(4)));
typedef __bf16 bf16x8_t __attribute__((ext_vector_type(8)));

__device__ __forceinline__ unsigned short f2bf(float f) {
    __hip_bfloat16 h = __float2bfloat16(f);
    return __builtin_bit_cast(unsigned short, h);
}

// async global->LDS, 16B/lane; LDS dest is wave-uniform base + lane*16.
__device__ __forceinline__ void gld_lds16(void* lds, const void* gp) {
#if __has_builtin(__builtin_amdgcn_global_load_lds)
    __builtin_amdgcn_global_load_lds(
        (const __attribute__((address_space(1))) unsigned int*)gp,
        (__attribute__((address_space(3))) unsigned int*)lds, 16, 0, 0);
#else
    *(uint4*)lds = *(const uint4*)gp;
#endif
}

// ---------------- ws layout ----------------
// kp     : float [T][CI][CO]              32768 f
// escale : float [B][T][N]                65536 f
// bns    : float sum[64]+sumsq[64]        128 f
// rowsum : float [B][N]                   8192 f
// He2    : float [2 part][B*N][64]        1048576 f  (4 MB)
// G      : bf16  [B][N][N]                8388608 us (16 MB)
// bmatT  : bf16  [B][512 col][N(m)]       4194304 us (8 MB)

// K0: repack k_tensor (CO,CI,T) -> kp[t][c][o]; also zero bns (replaces memset)
__global__ __launch_bounds__(256) void k_pack(const float* __restrict__ k,
                                              float* __restrict__ kp,
                                              float* __restrict__ bns) {
    int i = blockIdx.x * 256 + threadIdx.x;   // 32768 total
    int o = i & 63;
    int c = (i >> 6) & 63;
    int t = i >> 12;
    kp[i] = k[(o * 64 + c) * 8 + t];
    if (blockIdx.x == 0 && threadIdx.x < 128) bns[threadIdx.x] = 0.f;
}

// K1: G[b][row][*] bf16 + rowsum. 1024 blocks = b(8) x 8-row chunk(128); 256 thr.
// Per-thread column octet held in REGISTERS across all 8 rows (conflict-free
// inner loop); G stores are 16B/lane fully coalesced.
__global__ __launch_bounds__(256) void k_g(const float* __restrict__ points,
                                           unsigned short* __restrict__ G,
                                           float* __restrict__ rowsum) {
    __shared__ float praw[3072];
    __shared__ float px[1024], py[1024], pz[1024], hq[1024];
    __shared__ float rs[8];

    const int b  = blockIdx.x & 7;               // XCD swizzle
    const int n0 = (blockIdx.x >> 3) * 8;
    const int tid = threadIdx.x;

    for (int i = tid; i < 3072; i += 256) praw[i] = points[b * 3072 + i];
    if (tid < 8) rs[tid] = 0.f;
    __syncthreads();
    for (int n = tid; n < 1024; n += 256) {
        float x = praw[n * 3], y = praw[n * 3 + 1], z = praw[n * 3 + 2];
        px[n] = x; py[n] = y; pz[n] = z;
        hq[n] = -0.5f * (x * x + y * y + z * z);
    }
    __syncthreads();

    const int rhalf = tid >> 7;                  // 0/1: which row of the pair
    const int c0 = (tid & 127) * 8;              // column octet
    // hoist column data into registers (one-time LDS reads)
    float vx[8], vy[8], vz[8], vh[8];
    *(float4*)&vx[0] = *(const float4*)&px[c0];
    *(float4*)&vx[4] = *(const float4*)&px[c0 + 4];
    *(float4*)&vy[0] = *(const float4*)&py[c0];
    *(float4*)&vy[4] = *(const float4*)&py[c0 + 4];
    *(float4*)&vz[0] = *(const float4*)&pz[c0];
    *(float4*)&vz[4] = *(const float4*)&pz[c0 + 4];
    *(float4*)&vh[0] = *(const float4*)&hq[c0];
    *(float4*)&vh[4] = *(const float4*)&hq[c0 + 4];

    unsigned short* gb = G + ((size_t)b << 20);

    #pragma unroll
    for (int u = 0; u < 4; ++u) {
        const int rl = u * 2 + rhalf;
        const int row = n0 + rl;
        const float rx = px[row], ry = py[row], rz = pz[row], hr = hq[row];
        unsigned short us[8];
        float ssum = 0.f;
        #pragma unroll
        for (int j = 0; j < 8; ++j) {
            float e = __expf(hr + vh[j] + rx * vx[j] + ry * vy[j] + rz * vz[j]);
            ssum += e;
            us[j] = f2bf(e);
        }
        uint4 pk;
        pk.x = us[0] | ((unsigned int)us[1] << 16);
        pk.y = us[2] | ((unsigned int)us[3] << 16);
        pk.z = us[4] | ((unsigned int)us[5] << 16);
        pk.w = us[6] | ((unsigned int)us[7] << 16);
        *(uint4*)(gb + (size_t)row * 1024 + c0) = pk;
        #pragma unroll
        for (int m = 32; m; m >>= 1) ssum += __shfl_xor(ssum, m, 64);
        if ((tid & 63) == 0) atomicAdd(&rs[rl], ssum);
    }
    __syncthreads();
    if (tid < 8) rowsum[b * 1024 + n0 + tid] = rs[tid];
}

// K2: light prep: w = funcs/rowsum; C_t = sfac*(w @ k_t^T) -> bmatT bf16; escale.
// 512 blocks = b(8) x 16-row chunk(64). wl stride 68: conflict-free broadcasts.
__global__ __launch_bounds__(256) void k_prep(const float* __restrict__ points,
                                              const float* __restrict__ trans,
                                              const float* __restrict__ funcs,
                                              const float* __restrict__ kp,
                                              const float* __restrict__ rowsum,
                                              unsigned short* __restrict__ bmatT,
                                              float* __restrict__ escale) {
    __shared__ float ktl[4096];
    __shared__ float wl[16 * 68];
    __shared__ float sfac[8 * 16];
    __shared__ float trl[24];
    __shared__ float tsql[8];
    __shared__ float rsuml[16];
    __shared__ unsigned short tile[512 * 16];   // [col=t*64+o][m]

    const int b = blockIdx.x & 7;
    const int m0 = (blockIdx.x >> 3) * 16;
    const int tid = threadIdx.x;

    if (tid < 24) trl[tid] = trans[b * 24 + tid];
    if (tid < 16) rsuml[tid] = rowsum[b * 1024 + m0 + tid];
    __syncthreads();
    if (tid < 8) {
        float x = trl[tid * 3], y = trl[tid * 3 + 1], z = trl[tid * 3 + 2];
        tsql[tid] = x * x + y * y + z * z;
    }
    {
        const int m = tid >> 4, c4 = (tid & 15) * 4;
        const float4 f = *(const float4*)&funcs[((size_t)(b * 1024) + m0 + m) * 64 + c4];
        const float inv = 1.f / rsuml[m];
        *(float4*)&wl[m * 68 + c4] = make_float4(f.x * inv, f.y * inv, f.z * inv, f.w * inv);
    }
    __syncthreads();
    if (tid < 128) {
        const int t = tid >> 4, m = tid & 15;
        const int n = m0 + m;
        const float* pp = &points[(size_t)(b * 1024 + n) * 3];
        const float ptd = pp[0] * trl[t * 3] + pp[1] * trl[t * 3 + 1] + pp[2] * trl[t * 3 + 2];
        sfac[t * 16 + m] = __expf(-ptd - 0.5f * tsql[t]);
        escale[(size_t)(b * 8 + t) * 1024 + n] = __expf(ptd);
    }

    for (int t = 0; t < 8; ++t) {
        __syncthreads();
        for (int i = tid; i < 4096; i += 256) ktl[i] = kp[t * 4096 + i];
        __syncthreads();
        const int m = tid >> 4, o4 = (tid & 15) * 4;
        float4 acc = make_float4(0.f, 0.f, 0.f, 0.f);
        const float* wrow = &wl[m * 68];
        #pragma unroll 8
        for (int c = 0; c < 64; ++c) {
            float wv = wrow[c];
            float4 k4 = *(const float4*)&ktl[c * 64 + o4];
            acc.x += wv * k4.x; acc.y += wv * k4.y;
            acc.z += wv * k4.z; acc.w += wv * k4.w;
        }
        const float sf = sfac[t * 16 + m];
        tile[(t * 64 + o4 + 0) * 16 + m] = f2bf(acc.x * sf);
        tile[(t * 64 + o4 + 1) * 16 + m] = f2bf(acc.y * sf);
        tile[(t * 64 + o4 + 2) * 16 + m] = f2bf(acc.z * sf);
        tile[(t * 64 + o4 + 3) * 16 + m] = f2bf(acc.w * sf);
    }
    __syncthreads();
    for (int U = tid; U < 4096; U += 256) {
        int col = U >> 3, mp = U & 7;
        unsigned int val = (unsigned int)tile[col * 16 + 2 * mp]
                         | ((unsigned int)tile[col * 16 + 2 * mp + 1] << 16);
        *((unsigned int*)bmatT + ((size_t)(b * 512 + col) * 512 + (m0 >> 1) + mp)) = val;
    }
}

// K3: bf16 GEMM with global_load_lds staging + XOR-4 k-group swizzle.
// grid 512 = b(8) x rt(8) x [og(4) x kh(2)]; 256 thr = 4 waves; 128x128 tile, BK=32.
// Block's 128 B-cols = all 8 t x 16 channels (og) -> full t-reduction in-block.
__global__ __launch_bounds__(256) void k_gemm(const unsigned short* __restrict__ G,
                                              const unsigned short* __restrict__ bmatT,
                                              const float* __restrict__ escale,
                                              float* __restrict__ He2) {
    __shared__ unsigned short As[4096];   // [row(128)][k(32)] bf16, k-swizzled
    __shared__ unsigned short Bs[4096];   // [c'(128)=t*16+oo][k(32)] bf16, k-swizzled
    __shared__ float escT[1024];          // [t(8)][row(128)]
    __shared__ float red[128 * 20];       // padded reduce tile [row][16ch]

    const int b  = blockIdx.x & 7;        // XCD swizzle
    const int rt = (blockIdx.x >> 3) & 7;
    const int z  = blockIdx.x >> 6;       // 0..7
    const int og = z & 3;                 // channel group (16 ch)
    const int kh = z >> 2;                // K half
    const int n0 = rt * 128;
    const int kb = kh * 512;

    const int tid  = threadIdx.x;
    const int wave = tid >> 6, lane = tid & 63;
    const int wr = wave >> 1, wc = wave & 1;

    {   // stage escale [8t][128 rows]
        const int t = tid >> 5, r4 = (tid & 31) * 4;
        *(float4*)&escT[t * 128 + r4] =
            *(const float4*)&escale[(size_t)(b * 8 + t) * 1024 + n0 + r4];
    }

    const unsigned short* gA = G + ((size_t)b << 20) + (size_t)n0 * 1024 + kb;
    const unsigned short* gB = bmatT + (size_t)(b * 512 + og * 16) * 1024 + kb;

    const int r16 = lane >> 2;            // row within 16-seg
    const int kq  = lane & 3;             // dest 16B k-group
    const int gsw = kq ^ (r16 & 3);       // swizzled source k-group
    const size_t gAoff = (size_t)r16 * 1024 + gsw * 8;

    f32x4_t acc[4][4];
    #pragma unroll
    for (int i = 0; i < 4; ++i)
        #pragma unroll
        for (int j = 0; j < 4; ++j) acc[i][j] = f32x4_t{0.f, 0.f, 0.f, 0.f};

    const int fr = lane & 15;             // fragment row/col part
    const int swoff = ((lane >> 4) ^ (fr & 3)) << 4;   // swizzled frag byte offset

    for (int kk = 0; kk < 16; ++kk) {
        const int k0 = kk * 32;
        __syncthreads();                  // all waves done with prev As/Bs
        #pragma unroll
        for (int i = 0; i < 2; ++i) {
            const int seg = wave * 2 + i;   // 16 rows (A) / one t: 16 cols (B)
            gld_lds16((char*)As + seg * 1024 + lane * 16,
                      gA + (size_t)(seg * 16) * 1024 + k0 + gAoff);
            gld_lds16((char*)Bs + seg * 1024 + lane * 16,
                      gB + (size_t)(seg * 64) * 1024 + (size_t)r16 * 1024 + k0 + gsw * 8);
        }
        __syncthreads();                  // DMA drained -> tiles visible
        uint4 afr[4], bfr[4];
        #pragma unroll
        for (int i = 0; i < 4; ++i)
            afr[i] = *(const uint4*)((const char*)As + (wr * 64 + i * 16 + fr) * 64 + swoff);
        #pragma unroll
        for (int j = 0; j < 4; ++j)
            bfr[j] = *(const uint4*)((const char*)Bs + (wc * 64 + j * 16 + fr) * 64 + swoff);
        #pragma unroll
        for (int i = 0; i < 4; ++i)
            #pragma unroll
            for (int j = 0; j < 4; ++j)
                acc[i][j] = __builtin_amdgcn_mfma_f32_16x16x32_bf16(
                    __builtin_bit_cast(bf16x8_t, afr[i]),
                    __builtin_bit_cast(bf16x8_t, bfr[j]),
                    acc[i][j], 0, 0, 0);
    }

    // epilogue: res[row][oo] = sum_j escale[wc*4+j][row] * acc[.][j][.]
    const int quad = lane >> 4, oo = lane & 15;
    float res[4][4];
    #pragma unroll
    for (int i = 0; i < 4; ++i)
        #pragma unroll
        for (int r = 0; r < 4; ++r) {
            const int lr = wr * 64 + i * 16 + quad * 4 + r;
            float s = 0.f;
            #pragma unroll
            for (int j = 0; j < 4; ++j)
                s += escT[(wc * 4 + j) * 128 + lr] * acc[i][j][r];
            res[i][r] = s;
        }
    if (wc == 0) {
        #pragma unroll
        for (int i = 0; i < 4; ++i)
            #pragma unroll
            for (int r = 0; r < 4; ++r) {
                const int lr = wr * 64 + i * 16 + quad * 4 + r;
                red[lr * 20 + oo] = res[i][r];
            }
    }
    __syncthreads();
    if (wc == 1) {
        #pragma unroll
        for (int i = 0; i < 4; ++i)
            #pragma unroll
            for (int r = 0; r < 4; ++r) {
                const int lr = wr * 64 + i * 16 + quad * 4 + r;
                red[lr * 20 + oo] += res[i][r];
            }
    }
    __syncthreads();
    float* dst = He2 + (size_t)kh * 524288 + (size_t)(b * 1024 + n0) * 64 + og * 16;
    #pragma unroll
    for (int it = 0; it < 2; ++it) {
        const int L = it * 256 + tid;
        const int row = L >> 2, c4 = (L & 3) * 4;
        *(float4*)(dst + (size_t)row * 64 + c4) = *(const float4*)&red[row * 20 + c4];
    }
}

// K4: out = He2[0] + He2[1]; fused BN sum/sumsq
__global__ __launch_bounds__(256) void k_fin(const float* __restrict__ He2,
                                             float* __restrict__ out,
                                             float* __restrict__ bns) {
    __shared__ float s1[16][64], s2[16][64];
    const int tid = threadIdx.x;
    const float4* H4 = (const float4*)He2;
    float a0 = 0.f, a1 = 0.f, a2 = 0.f, a3 = 0.f;
    float q0 = 0.f, q1 = 0.f, q2 = 0.f, q3 = 0.f;
    #pragma unroll
    for (int it = 0; it < 2; ++it) {
        const size_t idx = (size_t)blockIdx.x * 512 + it * 256 + tid;
        float4 p0 = H4[idx];
        float4 p1 = H4[131072 + idx];
        float4 s = make_float4(p0.x + p1.x, p0.y + p1.y, p0.z + p1.z, p0.w + p1.w);
        ((float4*)out)[idx] = s;
        a0 += s.x; a1 += s.y; a2 += s.z; a3 += s.w;
        q0 += s.x * s.x; q1 += s.y * s.y; q2 += s.z * s.z; q3 += s.w * s.w;
    }
    const int g = tid >> 4, o4 = (tid & 15) * 4;
    *(float4*)&s1[g][o4] = make_float4(a0, a1, a2, a3);
    *(float4*)&s2[g][o4] = make_float4(q0, q1, q2, q3);
    __syncthreads();
    if (tid < 64) {
        float sa = 0.f, sb = 0.f;
        #pragma unroll
        for (int r = 0; r < 16; ++r) { sa += s1[r][tid]; sb += s2[r][tid]; }
        atomicAdd(&bns[tid], sa);
        atomicAdd(&bns[64 + tid], sb);
    }
}

// K5: in-place BN (training stats) + ReLU
__global__ __launch_bounds__(256) void k_bn(float* __restrict__ out,
                                            const float* __restrict__ bns,
                                            const float* __restrict__ gamma,
                                            const float* __restrict__ beta) {
    const int i = blockIdx.x * 256 + threadIdx.x;
    const int o4 = (i & 15) * 4;
    float4 x = ((float4*)out)[i];
    const float4 s  = *(const float4*)&bns[o4];
    const float4 s2 = *(const float4*)&bns[64 + o4];
    const float4 gm = *(const float4*)&gamma[o4];
    const float4 bt = *(const float4*)&beta[o4];
    const float invn = 1.f / 8192.f;
    float m, v, w;
    m = s.x * invn; v = s2.x * invn - m * m; w = __frsqrt_rn(v + BN_EPS) * gm.x;
    x.x = fmaxf((x.x - m) * w + bt.x, 0.f);
    m = s.y * invn; v = s2.y * invn - m * m; w = __frsqrt_rn(v + BN_EPS) * gm.y;
    x.y = fmaxf((x.y - m) * w + bt.y, 0.f);
    m = s.z * invn; v = s2.z * invn - m * m; w = __frsqrt_rn(v + BN_EPS) * gm.z;
    x.z = fmaxf((x.z - m) * w + bt.z, 0.f);
    m = s.w * invn; v = s2.w * invn - m * m; w = __frsqrt_rn(v + BN_EPS) * gm.w;
    x.w = fmaxf((x.w - m) * w + bt.w, 0.f);
    ((float4*)out)[i] = x;
}

extern "C" void kernel_launch(void* const* d_in, const int* in_sizes, int n_in,
                              void* d_out, int out_size, void* d_ws, size_t ws_size,
                              hipStream_t stream) {
    const float* points = (const float*)d_in[0];
    const float* trans  = (const float*)d_in[1];
    const float* funcs  = (const float*)d_in[2];
    const float* ktens  = (const float*)d_in[3];
    const float* gamma  = (const float*)d_in[4];
    const float* beta   = (const float*)d_in[5];
    float* out = (float*)d_out;

    float* ws      = (float*)d_ws;
    float* kp      = ws;                    // 32768 f
    float* escale  = kp + 32768;            // 65536 f
    float* bns     = escale + 65536;        // 128 f
    float* rowsum  = bns + 128;             // 8192 f
    float* He2     = rowsum + 8192;         // 1048576 f
    unsigned short* G     = (unsigned short*)(He2 + 1048576);   // 8388608 us
    unsigned short* bmatT = G + 8388608;                        // 4194304 us

    k_pack<<<128, 256, 0, stream>>>(ktens, kp, bns);
    k_g<<<1024, 256, 0, stream>>>(points, G, rowsum);
    k_prep<<<512, 256, 0, stream>>>(points, trans, funcs, kp, rowsum, bmatT, escale);
    k_gemm<<<512, 256, 0, stream>>>(G, bmatT, escale, He2);
    k_fin<<<256, 256, 0, stream>>>(He2, out, bns);
    k_bn<<<512, 256, 0, stream>>>(out, bns, gamma, beta);
}

// Round 6
// 118.133 us; speedup vs baseline: 1.2673x; 1.2134x over previous
//
#include <hip/hip_runtime.h>
#include <hip/hip_bf16.h>
#include <cstdint>
#include <cstddef>

#define BN_EPS 1e-5f

typedef float f32x4_t __attribute__((ext_vector_type(4)));
typedef __bf16 bf16x8_t __attribute__((ext_vector_type(8)));

__device__ __forceinline__ unsigned short f2bf(float f) {
    __hip_bfloat16 h = __float2bfloat16(f);
    return __builtin_bit_cast(unsigned short, h);
}

// async global->LDS, 16B/lane; LDS dest is wave-uniform base + lane*16.
__device__ __forceinline__ void gld_lds16(void* lds, const void* gp) {
#if __has_builtin(__builtin_amdgcn_global_load_lds)
    __builtin_amdgcn_global_load_lds(
        (const __attribute__((address_space(1))) unsigned int*)gp,
        (__attribute__((address_space(3))) unsigned int*)lds, 16, 0, 0);
#else
    *(uint4*)lds = *(const uint4*)gp;
#endif
}

// ---------------- ws layout ----------------
// kpb    : bf16  [512 col=t*64+o][64 c]   32768 us
// escale : float [B][T][N]                65536 f
// bns    : float sum[64]+sumsq[64]        128 f
// rowsum : float [B][N]                   8192 f
// He2    : float [4 part][B*N][64]        2097152 f  (8 MB)
// G      : bf16  [B][N][N]                8388608 us (16 MB)
// bmatT  : bf16  [B][512 col][N(m)]       4194304 us (8 MB)

// K1: blocks 0..1023: G[b][row][*] bf16 + rowsum (column octet in registers).
//     blocks 1024..1151: repack k_tensor -> kpb bf16 [t*64+o][c]; zero bns.
__global__ __launch_bounds__(256) void k_g(const float* __restrict__ points,
                                           const float* __restrict__ ktens,
                                           unsigned short* __restrict__ G,
                                           float* __restrict__ rowsum,
                                           unsigned short* __restrict__ kpb,
                                           float* __restrict__ bns) {
    __shared__ float praw[3072];
    __shared__ float px[1024], py[1024], pz[1024], hq[1024];
    __shared__ float rs[8];

    const int tid = threadIdx.x;
    if (blockIdx.x >= 1024) {             // pack branch (block-uniform)
        const int i = (blockIdx.x - 1024) * 256 + tid;   // i = (t*64+o)*64 + c
        const int t = i >> 12, o = (i >> 6) & 63, c = i & 63;
        kpb[i] = f2bf(ktens[(o * 64 + c) * 8 + t]);
        if (blockIdx.x == 1024 && tid < 128) bns[tid] = 0.f;
        return;
    }

    const int b  = blockIdx.x & 7;               // XCD swizzle
    const int n0 = (blockIdx.x >> 3) * 8;

    for (int i = tid; i < 3072; i += 256) praw[i] = points[b * 3072 + i];
    if (tid < 8) rs[tid] = 0.f;
    __syncthreads();
    for (int n = tid; n < 1024; n += 256) {
        float x = praw[n * 3], y = praw[n * 3 + 1], z = praw[n * 3 + 2];
        px[n] = x; py[n] = y; pz[n] = z;
        hq[n] = -0.5f * (x * x + y * y + z * z);
    }
    __syncthreads();

    const int rhalf = tid >> 7;                  // 0/1: which row of the pair
    const int c0 = (tid & 127) * 8;              // column octet
    float vx[8], vy[8], vz[8], vh[8];
    *(float4*)&vx[0] = *(const float4*)&px[c0];
    *(float4*)&vx[4] = *(const float4*)&px[c0 + 4];
    *(float4*)&vy[0] = *(const float4*)&py[c0];
    *(float4*)&vy[4] = *(const float4*)&py[c0 + 4];
    *(float4*)&vz[0] = *(const float4*)&pz[c0];
    *(float4*)&vz[4] = *(const float4*)&pz[c0 + 4];
    *(float4*)&vh[0] = *(const float4*)&hq[c0];
    *(float4*)&vh[4] = *(const float4*)&hq[c0 + 4];

    unsigned short* gb = G + ((size_t)b << 20);

    #pragma unroll
    for (int u = 0; u < 4; ++u) {
        const int rl = u * 2 + rhalf;
        const int row = n0 + rl;
        const float rx = px[row], ry = py[row], rz = pz[row], hr = hq[row];
        unsigned short us[8];
        float ssum = 0.f;
        #pragma unroll
        for (int j = 0; j < 8; ++j) {
            float e = __expf(hr + vh[j] + rx * vx[j] + ry * vy[j] + rz * vz[j]);
            ssum += e;
            us[j] = f2bf(e);
        }
        uint4 pk;
        pk.x = us[0] | ((unsigned int)us[1] << 16);
        pk.y = us[2] | ((unsigned int)us[3] << 16);
        pk.z = us[4] | ((unsigned int)us[5] << 16);
        pk.w = us[6] | ((unsigned int)us[7] << 16);
        *(uint4*)(gb + (size_t)row * 1024 + c0) = pk;
        #pragma unroll
        for (int m = 32; m; m >>= 1) ssum += __shfl_xor(ssum, m, 64);
        if ((tid & 63) == 0) atomicAdd(&rs[rl], ssum);
    }
    __syncthreads();
    if (tid < 8) rowsum[b * 1024 + n0 + tid] = rs[tid];
}

// K2: MFMA prep GEMM: bmat[m][col] = (sfac[t,m]/rowsum[m]) * sum_c funcs[m,c]*kpb[col,c]
// grid 256 = b(8) x mt(8,128 rows) x ct(4,128 cols); 4 waves; K=64; also escale.
__global__ __launch_bounds__(256) void k_prep(const float* __restrict__ points,
                                              const float* __restrict__ trans,
                                              const float* __restrict__ funcs,
                                              const unsigned short* __restrict__ kpb,
                                              const float* __restrict__ rowsum,
                                              unsigned short* __restrict__ bmatT,
                                              float* __restrict__ escale) {
    __shared__ unsigned short Asm[128 * 72];   // [m][c] bf16, stride 72
    __shared__ unsigned short Bsm[128 * 72];   // [col][c] bf16, stride 72
    __shared__ float sfacl[256];               // [tloc(2)][m(128)]

    const int b  = blockIdx.x & 7;
    const int mt = (blockIdx.x >> 3) & 7;
    const int ct = blockIdx.x >> 6;            // 0..3 (t-pair)
    const int m0 = mt * 128;

    const int tid  = threadIdx.x;
    const int wave = tid >> 6, lane = tid & 63;
    const int wr = wave >> 1, wc = wave & 1;
    const int fr = lane & 15, quad = lane >> 4;

    // sfac + escale (global reads only; no LDS dependency)
    {
        const int tloc = tid >> 7, m = tid & 127;
        const int t = ct * 2 + tloc;
        const float tx = trans[b * 24 + t * 3], ty = trans[b * 24 + t * 3 + 1],
                    tz = trans[b * 24 + t * 3 + 2];
        const float* pp = &points[(size_t)(b * 1024 + m0 + m) * 3];
        const float ptd = pp[0] * tx + pp[1] * ty + pp[2] * tz;
        const float tsq = tx * tx + ty * ty + tz * tz;
        const float rsv = rowsum[b * 1024 + m0 + m];
        sfacl[tloc * 128 + m] = __expf(-ptd - 0.5f * tsq) / rsv;
        escale[(size_t)(b * 8 + t) * 1024 + m0 + m] = __expf(ptd);
    }
    // stage A: funcs fp32 -> bf16 LDS [m][c]
    #pragma unroll
    for (int rep = 0; rep < 2; ++rep) {
        const int m = rep * 64 + (tid >> 2);
        const int c16 = (tid & 3) * 16;
        const float* fp = &funcs[((size_t)(b * 1024) + m0 + m) * 64 + c16];
        float4 f0 = *(const float4*)fp, f1 = *(const float4*)(fp + 4);
        float4 f2 = *(const float4*)(fp + 8), f3 = *(const float4*)(fp + 12);
        uint4 p0, p1;
        p0.x = f2bf(f0.x) | ((unsigned)f2bf(f0.y) << 16);
        p0.y = f2bf(f0.z) | ((unsigned)f2bf(f0.w) << 16);
        p0.z = f2bf(f1.x) | ((unsigned)f2bf(f1.y) << 16);
        p0.w = f2bf(f1.z) | ((unsigned)f2bf(f1.w) << 16);
        p1.x = f2bf(f2.x) | ((unsigned)f2bf(f2.y) << 16);
        p1.y = f2bf(f2.z) | ((unsigned)f2bf(f2.w) << 16);
        p1.z = f2bf(f3.x) | ((unsigned)f2bf(f3.y) << 16);
        p1.w = f2bf(f3.z) | ((unsigned)f2bf(f3.w) << 16);
        *(uint4*)&Asm[m * 72 + c16] = p0;
        *(uint4*)&Asm[m * 72 + c16 + 8] = p1;
    }
    // stage B: kpb bf16 -> LDS [col][c]
    #pragma unroll
    for (int rep = 0; rep < 4; ++rep) {
        const int col = rep * 32 + (tid >> 3);
        const int c8 = (tid & 7) * 8;
        uint4 v = *(const uint4*)&kpb[(size_t)(ct * 128 + col) * 64 + c8];
        *(uint4*)&Bsm[col * 72 + c8] = v;
    }
    __syncthreads();

    f32x4_t acc[4][4];
    #pragma unroll
    for (int i = 0; i < 4; ++i)
        #pragma unroll
        for (int j = 0; j < 4; ++j) acc[i][j] = f32x4_t{0.f, 0.f, 0.f, 0.f};

    #pragma unroll
    for (int s = 0; s < 2; ++s) {
        uint4 afr[4], bfr[4];
        #pragma unroll
        for (int i = 0; i < 4; ++i)
            afr[i] = *(const uint4*)&Asm[(wr * 64 + i * 16 + fr) * 72 + s * 32 + quad * 8];
        #pragma unroll
        for (int j = 0; j < 4; ++j)
            bfr[j] = *(const uint4*)&Bsm[(wc * 64 + j * 16 + fr) * 72 + s * 32 + quad * 8];
        #pragma unroll
        for (int i = 0; i < 4; ++i)
            #pragma unroll
            for (int j = 0; j < 4; ++j)
                acc[i][j] = __builtin_amdgcn_mfma_f32_16x16x32_bf16(
                    __builtin_bit_cast(bf16x8_t, afr[i]),
                    __builtin_bit_cast(bf16x8_t, bfr[j]),
                    acc[i][j], 0, 0, 0);
    }

    // epilogue: scale and pack 4 consecutive m per lane -> bmatT[b][col][m]
    #pragma unroll
    for (int i = 0; i < 4; ++i) {
        #pragma unroll
        for (int j = 0; j < 4; ++j) {
            const int colg = ct * 128 + wc * 64 + j * 16 + fr;
            ushort4 pk;
            {
                const int mb = wr * 64 + i * 16 + quad * 4;
                pk.x = f2bf(acc[i][j][0] * sfacl[wc * 128 + mb + 0]);
                pk.y = f2bf(acc[i][j][1] * sfacl[wc * 128 + mb + 1]);
                pk.z = f2bf(acc[i][j][2] * sfacl[wc * 128 + mb + 2]);
                pk.w = f2bf(acc[i][j][3] * sfacl[wc * 128 + mb + 3]);
                *(ushort4*)&bmatT[(size_t)(b * 512 + colg) * 1024 + m0 + mb] = pk;
            }
        }
    }
}

// K3: bf16 GEMM with global_load_lds staging + XOR-4 k-group swizzle.
// grid 1024 = b(8) x rt(8) x [og(4) x kh(4)]; 4 waves; 128x128 tile, BK=32, K/4=256.
__global__ __launch_bounds__(256) void k_gemm(const unsigned short* __restrict__ G,
                                              const unsigned short* __restrict__ bmatT,
                                              const float* __restrict__ escale,
                                              float* __restrict__ He2) {
    __shared__ unsigned short As[4096];   // [row(128)][k(32)] bf16, k-swizzled
    __shared__ unsigned short Bs[4096];   // [c'(128)=t*16+oo][k(32)] bf16, k-swizzled
    __shared__ float escT[1024];          // [t(8)][row(128)]
    __shared__ float red[128 * 20];       // padded reduce tile [row][16ch]

    const int b  = blockIdx.x & 7;        // XCD swizzle
    const int rt = (blockIdx.x >> 3) & 7;
    const int z  = blockIdx.x >> 6;       // 0..15
    const int og = z & 3;                 // channel group (16 ch)
    const int kh = z >> 2;                // K quarter
    const int n0 = rt * 128;
    const int kb = kh * 256;

    const int tid  = threadIdx.x;
    const int wave = tid >> 6, lane = tid & 63;
    const int wr = wave >> 1, wc = wave & 1;

    {   // stage escale [8t][128 rows]
        const int t = tid >> 5, r4 = (tid & 31) * 4;
        *(float4*)&escT[t * 128 + r4] =
            *(const float4*)&escale[(size_t)(b * 8 + t) * 1024 + n0 + r4];
    }

    const unsigned short* gA = G + ((size_t)b << 20) + (size_t)n0 * 1024 + kb;
    const unsigned short* gB = bmatT + (size_t)(b * 512 + og * 16) * 1024 + kb;

    const int r16 = lane >> 2;            // row within 16-seg
    const int kq  = lane & 3;             // dest 16B k-group
    const int gsw = kq ^ (r16 & 3);       // swizzled source k-group
    const size_t gAoff = (size_t)r16 * 1024 + gsw * 8;

    f32x4_t acc[4][4];
    #pragma unroll
    for (int i = 0; i < 4; ++i)
        #pragma unroll
        for (int j = 0; j < 4; ++j) acc[i][j] = f32x4_t{0.f, 0.f, 0.f, 0.f};

    const int fr = lane & 15;             // fragment row/col part
    const int swoff = ((lane >> 4) ^ (fr & 3)) << 4;   // swizzled frag byte offset

    for (int kk = 0; kk < 8; ++kk) {
        const int k0 = kk * 32;
        __syncthreads();                  // all waves done with prev As/Bs
        #pragma unroll
        for (int i = 0; i < 2; ++i) {
            const int seg = wave * 2 + i;   // 16 rows (A) / one t: 16 cols (B)
            gld_lds16((char*)As + seg * 1024 + lane * 16,
                      gA + (size_t)(seg * 16) * 1024 + k0 + gAoff);
            gld_lds16((char*)Bs + seg * 1024 + lane * 16,
                      gB + (size_t)(seg * 64) * 1024 + (size_t)r16 * 1024 + k0 + gsw * 8);
        }
        __syncthreads();                  // DMA drained -> tiles visible
        uint4 afr[4], bfr[4];
        #pragma unroll
        for (int i = 0; i < 4; ++i)
            afr[i] = *(const uint4*)((const char*)As + (wr * 64 + i * 16 + fr) * 64 + swoff);
        #pragma unroll
        for (int j = 0; j < 4; ++j)
            bfr[j] = *(const uint4*)((const char*)Bs + (wc * 64 + j * 16 + fr) * 64 + swoff);
        #pragma unroll
        for (int i = 0; i < 4; ++i)
            #pragma unroll
            for (int j = 0; j < 4; ++j)
                acc[i][j] = __builtin_amdgcn_mfma_f32_16x16x32_bf16(
                    __builtin_bit_cast(bf16x8_t, afr[i]),
                    __builtin_bit_cast(bf16x8_t, bfr[j]),
                    acc[i][j], 0, 0, 0);
    }

    // epilogue: res[row][oo] = sum_j escale[wc*4+j][row] * acc[.][j][.]
    const int quad = lane >> 4, oo = lane & 15;
    float res[4][4];
    #pragma unroll
    for (int i = 0; i < 4; ++i)
        #pragma unroll
        for (int r = 0; r < 4; ++r) {
            const int lr = wr * 64 + i * 16 + quad * 4 + r;
            float s = 0.f;
            #pragma unroll
            for (int j = 0; j < 4; ++j)
                s += escT[(wc * 4 + j) * 128 + lr] * acc[i][j][r];
            res[i][r] = s;
        }
    if (wc == 0) {
        #pragma unroll
        for (int i = 0; i < 4; ++i)
            #pragma unroll
            for (int r = 0; r < 4; ++r) {
                const int lr = wr * 64 + i * 16 + quad * 4 + r;
                red[lr * 20 + oo] = res[i][r];
            }
    }
    __syncthreads();
    if (wc == 1) {
        #pragma unroll
        for (int i = 0; i < 4; ++i)
            #pragma unroll
            for (int r = 0; r < 4; ++r) {
                const int lr = wr * 64 + i * 16 + quad * 4 + r;
                red[lr * 20 + oo] += res[i][r];
            }
    }
    __syncthreads();
    float* dst = He2 + (size_t)kh * 524288 + (size_t)(b * 1024 + n0) * 64 + og * 16;
    #pragma unroll
    for (int it = 0; it < 2; ++it) {
        const int L = it * 256 + tid;
        const int row = L >> 2, c4 = (L & 3) * 4;
        *(float4*)(dst + (size_t)row * 64 + c4) = *(const float4*)&red[row * 20 + c4];
    }
}

// K4: out = sum of 4 He2 partials; fused BN sum/sumsq
__global__ __launch_bounds__(256) void k_fin(const float* __restrict__ He2,
                                             float* __restrict__ out,
                                             float* __restrict__ bns) {
    __shared__ float s1[16][64], s2[16][64];
    const int tid = threadIdx.x;
    const float4* H4 = (const float4*)He2;
    float a0 = 0.f, a1 = 0.f, a2 = 0.f, a3 = 0.f;
    float q0 = 0.f, q1 = 0.f, q2 = 0.f, q3 = 0.f;
    #pragma unroll
    for (int it = 0; it < 2; ++it) {
        const size_t idx = (size_t)blockIdx.x * 512 + it * 256 + tid;
        float4 s = make_float4(0.f, 0.f, 0.f, 0.f);
        #pragma unroll
        for (int p = 0; p < 4; ++p) {
            float4 h = H4[(size_t)p * 131072 + idx];
            s.x += h.x; s.y += h.y; s.z += h.z; s.w += h.w;
        }
        ((float4*)out)[idx] = s;
        a0 += s.x; a1 += s.y; a2 += s.z; a3 += s.w;
        q0 += s.x * s.x; q1 += s.y * s.y; q2 += s.z * s.z; q3 += s.w * s.w;
    }
    const int g = tid >> 4, o4 = (tid & 15) * 4;
    *(float4*)&s1[g][o4] = make_float4(a0, a1, a2, a3);
    *(float4*)&s2[g][o4] = make_float4(q0, q1, q2, q3);
    __syncthreads();
    if (tid < 64) {
        float sa = 0.f, sb = 0.f;
        #pragma unroll
        for (int r = 0; r < 16; ++r) { sa += s1[r][tid]; sb += s2[r][tid]; }
        atomicAdd(&bns[tid], sa);
        atomicAdd(&bns[64 + tid], sb);
    }
}

// K5: in-place BN (training stats) + ReLU
__global__ __launch_bounds__(256) void k_bn(float* __restrict__ out,
                                            const float* __restrict__ bns,
                                            const float* __restrict__ gamma,
                                            const float* __restrict__ beta) {
    const int i = blockIdx.x * 256 + threadIdx.x;
    const int o4 = (i & 15) * 4;
    float4 x = ((float4*)out)[i];
    const float4 s  = *(const float4*)&bns[o4];
    const float4 s2 = *(const float4*)&bns[64 + o4];
    const float4 gm = *(const float4*)&gamma[o4];
    const float4 bt = *(const float4*)&beta[o4];
    const float invn = 1.f / 8192.f;
    float m, v, w;
    m = s.x * invn; v = s2.x * invn - m * m; w = __frsqrt_rn(v + BN_EPS) * gm.x;
    x.x = fmaxf((x.x - m) * w + bt.x, 0.f);
    m = s.y * invn; v = s2.y * invn - m * m; w = __frsqrt_rn(v + BN_EPS) * gm.y;
    x.y = fmaxf((x.y - m) * w + bt.y, 0.f);
    m = s.z * invn; v = s2.z * invn - m * m; w = __frsqrt_rn(v + BN_EPS) * gm.z;
    x.z = fmaxf((x.z - m) * w + bt.z, 0.f);
    m = s.w * invn; v = s2.w * invn - m * m; w = __frsqrt_rn(v + BN_EPS) * gm.w;
    x.w = fmaxf((x.w - m) * w + bt.w, 0.f);
    ((float4*)out)[i] = x;
}

extern "C" void kernel_launch(void* const* d_in, const int* in_sizes, int n_in,
                              void* d_out, int out_size, void* d_ws, size_t ws_size,
                              hipStream_t stream) {
    const float* points = (const float*)d_in[0];
    const float* trans  = (const float*)d_in[1];
    const float* funcs  = (const float*)d_in[2];
    const float* ktens  = (const float*)d_in[3];
    const float* gamma  = (const float*)d_in[4];
    const float* beta   = (const float*)d_in[5];
    float* out = (float*)d_out;

    float* ws      = (float*)d_ws;
    float* escale  = ws;                    // 65536 f
    float* bns     = escale + 65536;        // 128 f
    float* rowsum  = bns + 128;             // 8192 f
    float* He2     = rowsum + 8192;         // 2097152 f
    unsigned short* kpb   = (unsigned short*)(He2 + 2097152);   // 32768 us
    unsigned short* G     = kpb + 32768;                        // 8388608 us
    unsigned short* bmatT = G + 8388608;                        // 4194304 us

    k_g<<<1152, 256, 0, stream>>>(points, ktens, G, rowsum, kpb, bns);
    k_prep<<<256, 256, 0, stream>>>(points, trans, funcs, kpb, rowsum, bmatT, escale);
    k_gemm<<<1024, 256, 0, stream>>>(G, bmatT, escale, He2);
    k_fin<<<256, 256, 0, stream>>>(He2, out, bns);
    k_bn<<<512, 256, 0, stream>>>(out, bns, gamma, beta);
}